// Round 1
// baseline (1220.686 us; speedup 1.0000x reference)
//
#include <hip/hip_runtime.h>

#define N_NODES 40000
#define N_EDGES 640000
#define D 128   // D_IN == D_OUT == 128

// ---------------------------------------------------------------------------
// K1: init out[v][:] = b[:]  (float4 per thread), and zero deg[] counters.
// d_out / d_ws are poisoned 0xAA before every launch, so we must fully init.
// ---------------------------------------------------------------------------
__global__ __launch_bounds__(256) void init_kernel(const float* __restrict__ b,
                                                   float* __restrict__ out,
                                                   float* __restrict__ deg) {
    int i = blockIdx.x * 256 + threadIdx.x;          // over N_NODES*32 float4s
    const float4* b4 = reinterpret_cast<const float4*>(b);
    float4* out4 = reinterpret_cast<float4*>(out);
    if (i < N_NODES * (D / 4)) {
        out4[i] = b4[i & (D / 4 - 1)];
    }
    if (i < N_NODES) deg[i] = 0.0f;
}

// ---------------------------------------------------------------------------
// K2: deg[dst[e]] += 1   (in-degree count; hardware f32 atomic, exact < 2^24)
// ---------------------------------------------------------------------------
__global__ __launch_bounds__(256) void degree_kernel(const int* __restrict__ dst,
                                                     float* __restrict__ deg) {
    int e = blockIdx.x * 256 + threadIdx.x;
    if (e < N_EDGES) unsafeAtomicAdd(&deg[dst[e]], 1.0f);
}

// ---------------------------------------------------------------------------
// K3: deg -> inv_deg in place
// ---------------------------------------------------------------------------
__global__ __launch_bounds__(256) void invdeg_kernel(float* __restrict__ deg) {
    int v = blockIdx.x * 256 + threadIdx.x;
    if (v < N_NODES) {
        float d = deg[v];
        deg[v] = (d > 0.0f) ? (1.0f / d) : 0.0f;
    }
}

// ---------------------------------------------------------------------------
// K4: y = x @ W   (fp32 vector GEMM; no fp32 MFMA on CDNA4).
// Block = 256 threads computes a 16-row x 128-col tile.
//   thread: lane = tid&31 -> cols [lane*4, lane*4+4); rp = tid>>5 -> rows 2rp, 2rp+1
// W (64 KB) + x tile (8 KB) staged in LDS. float4 LDS reads, conflict-light.
// ---------------------------------------------------------------------------
__global__ __launch_bounds__(256) void gemm_xw_kernel(const float* __restrict__ x,
                                                      const float* __restrict__ W,
                                                      float* __restrict__ y) {
    __shared__ float Ws[D * D];       // 64 KB, [k][c] row-major
    __shared__ float xs[16 * D];      // 8 KB
    const int tid = threadIdx.x;
    const int rowbase = blockIdx.x * 16;          // 40000/16 = 2500 blocks exact

    float4* Ws4 = reinterpret_cast<float4*>(Ws);
    const float4* W4 = reinterpret_cast<const float4*>(W);
#pragma unroll
    for (int i = 0; i < 16; ++i)                  // 4096 float4 / 256 thr = 16
        Ws4[tid + i * 256] = W4[tid + i * 256];

    float4* xs4 = reinterpret_cast<float4*>(xs);
    const float4* x4 = reinterpret_cast<const float4*>(x) + rowbase * (D / 4);
    xs4[tid]       = x4[tid];
    xs4[tid + 256] = x4[tid + 256];
    __syncthreads();

    const int lane = tid & 31;
    const int rp   = tid >> 5;                    // 0..7
    const float* xrow0 = xs + (rp * 2) * D;
    const float* xrow1 = xrow0 + D;

    float4 acc0 = {0.f, 0.f, 0.f, 0.f};
    float4 acc1 = {0.f, 0.f, 0.f, 0.f};
#pragma unroll 4
    for (int k = 0; k < D; ++k) {
        float4 wv = Ws4[k * (D / 4) + lane];      // ds_read_b128, contiguous
        float xa = xrow0[k];                      // LDS broadcast
        float xb = xrow1[k];
        acc0.x += xa * wv.x; acc0.y += xa * wv.y; acc0.z += xa * wv.z; acc0.w += xa * wv.w;
        acc1.x += xb * wv.x; acc1.y += xb * wv.y; acc1.z += xb * wv.z; acc1.w += xb * wv.w;
    }

    float4* y4 = reinterpret_cast<float4*>(y);
    int r0 = rowbase + rp * 2;
    y4[r0 * (D / 4) + lane]       = acc0;
    y4[(r0 + 1) * (D / 4) + lane] = acc1;
}

// ---------------------------------------------------------------------------
// K5: scatter: out[dst[e]][:] += (inv_deg[dst[e]]*ew[e]) * y[src[e]][:]
// 32 lanes per edge, each lane owns one float4 (4 contiguous dims).
// ---------------------------------------------------------------------------
__global__ __launch_bounds__(256) void scatter_kernel(const int* __restrict__ src,
                                                      const int* __restrict__ dst,
                                                      const float* __restrict__ ew,
                                                      const float* __restrict__ invdeg,
                                                      const float* __restrict__ y,
                                                      float* __restrict__ out) {
    int gid = blockIdx.x * 256 + threadIdx.x;
    int e    = gid >> 5;
    int part = gid & 31;
    if (e >= N_EDGES) return;
    int s = src[e];
    int d = dst[e];
    float w = invdeg[d] * ew[e];
    float4 v = reinterpret_cast<const float4*>(y)[s * (D / 4) + part];
    float* o = out + d * D + part * 4;
    unsafeAtomicAdd(o + 0, w * v.x);
    unsafeAtomicAdd(o + 1, w * v.y);
    unsafeAtomicAdd(o + 2, w * v.z);
    unsafeAtomicAdd(o + 3, w * v.w);
}

// ---------------------------------------------------------------------------
extern "C" void kernel_launch(void* const* d_in, const int* in_sizes, int n_in,
                              void* d_out, int out_size, void* d_ws, size_t ws_size,
                              hipStream_t stream) {
    const float* x  = (const float*)d_in[0];
    const int*   src = (const int*)d_in[1];
    const int*   dst = (const int*)d_in[2];
    const float* ew = (const float*)d_in[3];
    const float* W  = (const float*)d_in[4];
    const float* b  = (const float*)d_in[5];
    float* out = (float*)d_out;

    // workspace layout: y [N_NODES*D floats] | deg [N_NODES floats]
    float* y   = (float*)d_ws;
    float* deg = y + (size_t)N_NODES * D;

    // K1: init out with bias, zero degree counters
    {
        int n = N_NODES * (D / 4);
        init_kernel<<<(n + 255) / 256, 256, 0, stream>>>(b, out, deg);
    }
    // K2: degree count
    degree_kernel<<<(N_EDGES + 255) / 256, 256, 0, stream>>>(dst, deg);
    // K3: invert
    invdeg_kernel<<<(N_NODES + 255) / 256, 256, 0, stream>>>(deg);
    // K4: y = x @ W
    gemm_xw_kernel<<<N_NODES / 16, 256, 0, stream>>>(x, W, y);
    // K5: weighted scatter-add into out
    {
        long long total = (long long)N_EDGES * 32;
        scatter_kernel<<<(int)((total + 255) / 256), 256, 0, stream>>>(src, dst, ew, deg, y, out);
    }
}

// Round 2
// 317.183 us; speedup vs baseline: 3.8485x; 3.8485x over previous
//
#include <hip/hip_runtime.h>

#define N_NODES 40000
#define N_EDGES 640000
#define D 128   // D_IN == D_OUT == 128

// ---------------------------------------------------------------------------
// Workspace layout (all 16B-aligned):
//   y       : N_NODES*D f32   (x @ W)
//   deg     : N_NODES int     (in-degree)
//   cursor  : N_NODES int     (bucket fill cursors)
//   invdeg  : N_NODES f32
//   offs    : N_NODES+1 int   (CSR row offsets by dst)
//   es      : N_EDGES int     (src sorted by dst)
//   ews     : N_EDGES f32     (invdeg[dst]*ew sorted by dst)
// ---------------------------------------------------------------------------

// K1: zero deg + cursor
__global__ __launch_bounds__(256) void init_kernel(int* __restrict__ deg,
                                                   int* __restrict__ cursor) {
    int i = blockIdx.x * 256 + threadIdx.x;
    if (i < N_NODES) { deg[i] = 0; cursor[i] = 0; }
}

// K2: deg[dst[e]]++  (640k int atomics over 160 KB -> L2-resident)
__global__ __launch_bounds__(256) void degree_kernel(const int* __restrict__ dst,
                                                     int* __restrict__ deg) {
    int e = blockIdx.x * 256 + threadIdx.x;
    if (e < N_EDGES) atomicAdd(&deg[e < N_EDGES ? dst[e] : 0], 1);
}

// K3: single-block exclusive scan of deg -> offs, plus invdeg.
// 1024 threads x 40 elements = 40960 >= 40000.
__global__ __launch_bounds__(1024) void scan_kernel(const int* __restrict__ deg,
                                                    int* __restrict__ offs,
                                                    float* __restrict__ invdeg) {
    __shared__ int sums[1024];
    const int t = threadIdx.x;
    const int base = t * 40;
    int s = 0;
    for (int i = 0; i < 40; ++i) {
        int idx = base + i;
        if (idx < N_NODES) s += deg[idx];
    }
    sums[t] = s;
    __syncthreads();
    // Hillis-Steele inclusive scan over 1024 thread sums
    for (int off = 1; off < 1024; off <<= 1) {
        int v = (t >= off) ? sums[t - off] : 0;
        __syncthreads();
        sums[t] += v;
        __syncthreads();
    }
    int running = sums[t] - s;   // exclusive prefix of this thread's chunk
    for (int i = 0; i < 40; ++i) {
        int idx = base + i;
        if (idx < N_NODES) {
            offs[idx] = running;
            int d = deg[idx];
            invdeg[idx] = (d > 0) ? (1.0f / (float)d) : 0.0f;
            running += d;
        }
    }
    if (t == 0) offs[N_NODES] = N_EDGES;
}

// K4: bucket edges by dst: es[pos]=src, ews[pos]=ew*invdeg[dst]
__global__ __launch_bounds__(256) void bucket_kernel(const int* __restrict__ src,
                                                     const int* __restrict__ dst,
                                                     const float* __restrict__ ew,
                                                     const float* __restrict__ invdeg,
                                                     const int* __restrict__ offs,
                                                     int* __restrict__ cursor,
                                                     int* __restrict__ es,
                                                     float* __restrict__ ews) {
    int e = blockIdx.x * 256 + threadIdx.x;
    if (e >= N_EDGES) return;
    int d = dst[e];
    int pos = offs[d] + atomicAdd(&cursor[d], 1);
    es[pos] = src[e];
    ews[pos] = ew[e] * invdeg[d];
}

// K5: y = x @ W (fp32 vector GEMM; no fp32 MFMA on CDNA4).
// Block = 256 threads computes a 16-row x 128-col tile; W+tile in LDS.
__global__ __launch_bounds__(256) void gemm_xw_kernel(const float* __restrict__ x,
                                                      const float* __restrict__ W,
                                                      float* __restrict__ y) {
    __shared__ float Ws[D * D];       // 64 KB, [k][c] row-major
    __shared__ float xs[16 * D];      // 8 KB
    const int tid = threadIdx.x;
    const int rowbase = blockIdx.x * 16;          // 40000/16 = 2500 blocks exact

    float4* Ws4 = reinterpret_cast<float4*>(Ws);
    const float4* W4 = reinterpret_cast<const float4*>(W);
#pragma unroll
    for (int i = 0; i < 16; ++i)
        Ws4[tid + i * 256] = W4[tid + i * 256];

    float4* xs4 = reinterpret_cast<float4*>(xs);
    const float4* x4 = reinterpret_cast<const float4*>(x) + rowbase * (D / 4);
    xs4[tid]       = x4[tid];
    xs4[tid + 256] = x4[tid + 256];
    __syncthreads();

    const int lane = tid & 31;
    const int rp   = tid >> 5;                    // 0..7
    const float* xrow0 = xs + (rp * 2) * D;
    const float* xrow1 = xrow0 + D;

    float4 acc0 = {0.f, 0.f, 0.f, 0.f};
    float4 acc1 = {0.f, 0.f, 0.f, 0.f};
#pragma unroll 4
    for (int k = 0; k < D; ++k) {
        float4 wv = Ws4[k * (D / 4) + lane];      // ds_read_b128, contiguous
        float xa = xrow0[k];                      // LDS broadcast
        float xb = xrow1[k];
        acc0.x += xa * wv.x; acc0.y += xa * wv.y; acc0.z += xa * wv.z; acc0.w += xa * wv.w;
        acc1.x += xb * wv.x; acc1.y += xb * wv.y; acc1.z += xb * wv.z; acc1.w += xb * wv.w;
    }

    float4* y4 = reinterpret_cast<float4*>(y);
    int r0 = rowbase + rp * 2;
    y4[r0 * (D / 4) + lane]       = acc0;
    y4[(r0 + 1) * (D / 4) + lane] = acc1;
}

// K6: per-node gather-reduce. 32 lanes per node, one float4 per lane.
// out[v][:] = sum_e ews[e] * y[es[e]][:] + b[:]
__global__ __launch_bounds__(256) void gather_kernel(const int* __restrict__ offs,
                                                     const int* __restrict__ es,
                                                     const float* __restrict__ ews,
                                                     const float* __restrict__ y,
                                                     const float* __restrict__ b,
                                                     float* __restrict__ out) {
    int gid = blockIdx.x * 256 + threadIdx.x;
    int v    = gid >> 5;
    int part = gid & 31;
    if (v >= N_NODES) return;
    int beg = offs[v];
    int end = offs[v + 1];
    const float4* y4 = reinterpret_cast<const float4*>(y);
    float4 acc = {0.f, 0.f, 0.f, 0.f};
    for (int e = beg; e < end; ++e) {
        int s   = es[e];     // uniform across the 32-lane group -> broadcast
        float w = ews[e];
        float4 t = y4[s * (D / 4) + part];
        acc.x += w * t.x; acc.y += w * t.y; acc.z += w * t.z; acc.w += w * t.w;
    }
    float4 bv = reinterpret_cast<const float4*>(b)[part];
    acc.x += bv.x; acc.y += bv.y; acc.z += bv.z; acc.w += bv.w;
    reinterpret_cast<float4*>(out)[v * (D / 4) + part] = acc;
}

// ---------------------------------------------------------------------------
extern "C" void kernel_launch(void* const* d_in, const int* in_sizes, int n_in,
                              void* d_out, int out_size, void* d_ws, size_t ws_size,
                              hipStream_t stream) {
    const float* x   = (const float*)d_in[0];
    const int*   src = (const int*)d_in[1];
    const int*   dst = (const int*)d_in[2];
    const float* ew  = (const float*)d_in[3];
    const float* W   = (const float*)d_in[4];
    const float* b   = (const float*)d_in[5];
    float* out = (float*)d_out;

    char* ws = (char*)d_ws;
    float* y      = (float*)ws;                       ws += (size_t)N_NODES * D * 4;
    int*   deg    = (int*)ws;                         ws += (size_t)N_NODES * 4;
    int*   cursor = (int*)ws;                         ws += (size_t)N_NODES * 4;
    float* invdeg = (float*)ws;                       ws += (size_t)N_NODES * 4;
    int*   offs   = (int*)ws;                         ws += (size_t)(N_NODES + 16) * 4;
    int*   es     = (int*)ws;                         ws += (size_t)N_EDGES * 4;
    float* ews    = (float*)ws;

    init_kernel<<<(N_NODES + 255) / 256, 256, 0, stream>>>(deg, cursor);
    degree_kernel<<<(N_EDGES + 255) / 256, 256, 0, stream>>>(dst, deg);
    scan_kernel<<<1, 1024, 0, stream>>>(deg, offs, invdeg);
    gemm_xw_kernel<<<N_NODES / 16, 256, 0, stream>>>(x, W, y);
    bucket_kernel<<<(N_EDGES + 255) / 256, 256, 0, stream>>>(src, dst, ew, invdeg,
                                                             offs, cursor, es, ews);
    {
        long long total = (long long)N_NODES * 32;
        gather_kernel<<<(int)((total + 255) / 256), 256, 0, stream>>>(offs, es, ews, y, b, out);
    }
}

// Round 4
// 223.304 us; speedup vs baseline: 5.4665x; 1.4204x over previous
//
#include <hip/hip_runtime.h>

#define N_NODES 40000
#define N_EDGES 640000
#define D 128                 // D_IN == D_OUT == 128
#define NB 157                // ceil(N_NODES / 256) scan blocks

// ---------------------------------------------------------------------------
// Workspace layout (all 16B-aligned):
//   y       : N_NODES*D f32   (x @ W)
//   deg     : N_NODES int     (in-degree)
//   cursor  : N_NODES int     (bucket fill cursors)
//   invdeg  : N_NODES f32
//   offs    : N_NODES+1 int   (CSR row offsets by dst)
//   bsum    : NB int          (per-block degree sums for scan)
//   es      : N_EDGES int     (src sorted by dst)
//   ews     : N_EDGES f32     (invdeg[dst]*ew sorted by dst)
// ---------------------------------------------------------------------------

// K1: zero deg + cursor
__global__ __launch_bounds__(256) void init_kernel(int* __restrict__ deg,
                                                   int* __restrict__ cursor) {
    int i = blockIdx.x * 256 + threadIdx.x;
    if (i < N_NODES) { deg[i] = 0; cursor[i] = 0; }
}

// K2: deg[dst[e]]++  (640k int atomics over 160 KB -> L2-resident)
__global__ __launch_bounds__(256) void degree_kernel(const int* __restrict__ dst,
                                                     int* __restrict__ deg) {
    int e = blockIdx.x * 256 + threadIdx.x;
    if (e < N_EDGES) atomicAdd(&deg[dst[e]], 1);
}

// K3a: per-block (256-node) sum of deg -> bsum[block]
__global__ __launch_bounds__(256) void reduce_kernel(const int* __restrict__ deg,
                                                     int* __restrict__ bsum) {
    __shared__ int s[256];
    int t = threadIdx.x;
    int idx = blockIdx.x * 256 + t;
    s[t] = (idx < N_NODES) ? deg[idx] : 0;
    __syncthreads();
#pragma unroll
    for (int off = 128; off > 0; off >>= 1) {
        if (t < off) s[t] += s[t + off];
        __syncthreads();
    }
    if (t == 0) bsum[blockIdx.x] = s[0];
}

// K3b: exclusive scan of bsum[NB] in one block (padded to 256)
__global__ __launch_bounds__(256) void scanb_kernel(int* __restrict__ bsum) {
    __shared__ int s[256];
    int t = threadIdx.x;
    int v = (t < NB) ? bsum[t] : 0;
    s[t] = v;
    __syncthreads();
#pragma unroll
    for (int off = 1; off < 256; off <<= 1) {
        int u = (t >= off) ? s[t - off] : 0;
        __syncthreads();
        s[t] += u;
        __syncthreads();
    }
    if (t < NB) bsum[t] = s[t] - v;   // exclusive prefix
}

// K3c: offs[idx] = bsum[blk] + exclusive_scan_within_block(deg); invdeg too.
__global__ __launch_bounds__(256) void offs_kernel(const int* __restrict__ deg,
                                                   const int* __restrict__ bsum,
                                                   int* __restrict__ offs,
                                                   float* __restrict__ invdeg) {
    __shared__ int s[256];
    int t = threadIdx.x;
    int idx = blockIdx.x * 256 + t;
    int d = (idx < N_NODES) ? deg[idx] : 0;
    s[t] = d;
    __syncthreads();
#pragma unroll
    for (int off = 1; off < 256; off <<= 1) {
        int u = (t >= off) ? s[t - off] : 0;
        __syncthreads();
        s[t] += u;
        __syncthreads();
    }
    int excl = s[t] - d + bsum[blockIdx.x];
    if (idx < N_NODES) {
        offs[idx] = excl;
        invdeg[idx] = (d > 0) ? (1.0f / (float)d) : 0.0f;
        if (idx == N_NODES - 1) offs[N_NODES] = excl + d;   // == N_EDGES
    }
}

// K4: bucket edges by dst: es[pos]=src, ews[pos]=ew*invdeg[dst]
__global__ __launch_bounds__(256) void bucket_kernel(const int* __restrict__ src,
                                                     const int* __restrict__ dst,
                                                     const float* __restrict__ ew,
                                                     const float* __restrict__ invdeg,
                                                     const int* __restrict__ offs,
                                                     int* __restrict__ cursor,
                                                     int* __restrict__ es,
                                                     float* __restrict__ ews) {
    int e = blockIdx.x * 256 + threadIdx.x;
    if (e >= N_EDGES) return;
    int d = dst[e];
    int pos = offs[d] + atomicAdd(&cursor[d], 1);
    es[pos] = src[e];
    ews[pos] = ew[e] * invdeg[d];
}

// K5: y = x @ W (fp32 vector GEMM; no fp32 MFMA on CDNA4).
// Block = 256 threads computes a 16-row x 128-col tile; W+tile in LDS.
__global__ __launch_bounds__(256) void gemm_xw_kernel(const float* __restrict__ x,
                                                      const float* __restrict__ W,
                                                      float* __restrict__ y) {
    __shared__ float Ws[D * D];       // 64 KB, [k][c] row-major
    __shared__ float xs[16 * D];      // 8 KB
    const int tid = threadIdx.x;
    const int rowbase = blockIdx.x * 16;          // 40000/16 = 2500 blocks exact

    float4* Ws4 = reinterpret_cast<float4*>(Ws);
    const float4* W4 = reinterpret_cast<const float4*>(W);
#pragma unroll
    for (int i = 0; i < 16; ++i)
        Ws4[tid + i * 256] = W4[tid + i * 256];

    float4* xs4 = reinterpret_cast<float4*>(xs);
    const float4* x4 = reinterpret_cast<const float4*>(x) + rowbase * (D / 4);
    xs4[tid]       = x4[tid];
    xs4[tid + 256] = x4[tid + 256];
    __syncthreads();

    const int lane = tid & 31;
    const int rp   = tid >> 5;                    // 0..7
    const float* xrow0 = xs + (rp * 2) * D;
    const float* xrow1 = xrow0 + D;

    float4 acc0 = {0.f, 0.f, 0.f, 0.f};
    float4 acc1 = {0.f, 0.f, 0.f, 0.f};
#pragma unroll 4
    for (int k = 0; k < D; ++k) {
        float4 wv = Ws4[k * (D / 4) + lane];      // ds_read_b128, contiguous
        float xa = xrow0[k];                      // LDS broadcast
        float xb = xrow1[k];
        acc0.x += xa * wv.x; acc0.y += xa * wv.y; acc0.z += xa * wv.z; acc0.w += xa * wv.w;
        acc1.x += xb * wv.x; acc1.y += xb * wv.y; acc1.z += xb * wv.z; acc1.w += xb * wv.w;
    }

    float4* y4 = reinterpret_cast<float4*>(y);
    int r0 = rowbase + rp * 2;
    y4[r0 * (D / 4) + lane]       = acc0;
    y4[(r0 + 1) * (D / 4) + lane] = acc1;
}

// K6: per-node gather-reduce. 32 lanes per node, one float4 per lane.
// Edge metadata loaded lane-parallel in chunks of 32, broadcast via shfl.
// out[v][:] = sum_e ews[e] * y[es[e]][:] + b[:]
__global__ __launch_bounds__(256) void gather_kernel(const int* __restrict__ offs,
                                                     const int* __restrict__ es,
                                                     const float* __restrict__ ews,
                                                     const float* __restrict__ y,
                                                     const float* __restrict__ b,
                                                     float* __restrict__ out) {
    int gid = blockIdx.x * 256 + threadIdx.x;
    int v    = gid >> 5;
    int part = gid & 31;
    if (v >= N_NODES) return;
    int beg = offs[v];
    int end = offs[v + 1];
    const float4* y4 = reinterpret_cast<const float4*>(y);
    float4 acc = {0.f, 0.f, 0.f, 0.f};
    for (int base = beg; base < end; base += 32) {
        int n = end - base; if (n > 32) n = 32;
        int   se = 0;
        float we = 0.0f;
        if (part < n) { se = es[base + part]; we = ews[base + part]; }
        for (int j = 0; j < n; ++j) {
            int   s = __shfl(se, j, 32);
            float w = __shfl(we, j, 32);
            float4 t = y4[s * (D / 4) + part];
            acc.x += w * t.x; acc.y += w * t.y; acc.z += w * t.z; acc.w += w * t.w;
        }
    }
    float4 bv = reinterpret_cast<const float4*>(b)[part];
    acc.x += bv.x; acc.y += bv.y; acc.z += bv.z; acc.w += bv.w;
    reinterpret_cast<float4*>(out)[v * (D / 4) + part] = acc;
}

// ---------------------------------------------------------------------------
extern "C" void kernel_launch(void* const* d_in, const int* in_sizes, int n_in,
                              void* d_out, int out_size, void* d_ws, size_t ws_size,
                              hipStream_t stream) {
    const float* x   = (const float*)d_in[0];
    const int*   src = (const int*)d_in[1];
    const int*   dst = (const int*)d_in[2];
    const float* ew  = (const float*)d_in[3];
    const float* W   = (const float*)d_in[4];
    const float* b   = (const float*)d_in[5];
    float* out = (float*)d_out;

    char* ws = (char*)d_ws;
    float* y      = (float*)ws;                       ws += (size_t)N_NODES * D * 4;
    int*   deg    = (int*)ws;                         ws += (size_t)N_NODES * 4;
    int*   cursor = (int*)ws;                         ws += (size_t)N_NODES * 4;
    float* invdeg = (float*)ws;                       ws += (size_t)N_NODES * 4;
    int*   offs   = (int*)ws;                         ws += (size_t)(N_NODES + 16) * 4;
    int*   bsum   = (int*)ws;                         ws += (size_t)((NB + 16) & ~3) * 4;
    int*   es     = (int*)ws;                         ws += (size_t)N_EDGES * 4;
    float* ews    = (float*)ws;

    init_kernel<<<(N_NODES + 255) / 256, 256, 0, stream>>>(deg, cursor);
    degree_kernel<<<(N_EDGES + 255) / 256, 256, 0, stream>>>(dst, deg);
    reduce_kernel<<<NB, 256, 0, stream>>>(deg, bsum);
    scanb_kernel<<<1, 256, 0, stream>>>(bsum);
    offs_kernel<<<NB, 256, 0, stream>>>(deg, bsum, offs, invdeg);
    gemm_xw_kernel<<<N_NODES / 16, 256, 0, stream>>>(x, W, y);
    bucket_kernel<<<(N_EDGES + 255) / 256, 256, 0, stream>>>(src, dst, ew, invdeg,
                                                             offs, cursor, es, ews);
    {
        long long total = (long long)N_NODES * 32;
        gather_kernel<<<(int)((total + 255) / 256), 256, 0, stream>>>(offs, es, ews, y, b, out);
    }
}

// Round 5
// 212.117 us; speedup vs baseline: 5.7548x; 1.0527x over previous
//
#include <hip/hip_runtime.h>

#define N_NODES 40000
#define N_EDGES 640000
#define D 128                 // D_IN == D_OUT == 128
#define NB 157                // ceil(N_NODES / 256) scan blocks
#define GEMM_ROWS 32          // rows per gemm block (40000/32 = 1250 exact)

// ---------------------------------------------------------------------------
// Workspace layout (all 16B-aligned):
//   y       : N_NODES*D f32    (x @ W)
//   deg     : N_NODES int      (in-degree)
//   cursor  : N_NODES int      (bucket fill cursors)
//   invdeg  : N_NODES f32
//   offs    : N_NODES+1 int    (CSR row offsets by dst)
//   bsum    : NB int           (per-block degree sums for scan)
//   pairs   : N_EDGES int2     (.x = src, .y = bits(ew)), sorted by dst
// ---------------------------------------------------------------------------

// K1: zero deg + cursor
__global__ __launch_bounds__(256) void init_kernel(int* __restrict__ deg,
                                                   int* __restrict__ cursor) {
    int i = blockIdx.x * 256 + threadIdx.x;
    if (i < N_NODES) { deg[i] = 0; cursor[i] = 0; }
}

// K2: deg[dst[e]]++  (640k int atomics over 160 KB -> L2-resident)
__global__ __launch_bounds__(256) void degree_kernel(const int* __restrict__ dst,
                                                     int* __restrict__ deg) {
    int e = blockIdx.x * 256 + threadIdx.x;
    if (e < N_EDGES) atomicAdd(&deg[dst[e]], 1);
}

// K3a: per-block (256-node) sum of deg -> bsum[block]
__global__ __launch_bounds__(256) void reduce_kernel(const int* __restrict__ deg,
                                                     int* __restrict__ bsum) {
    __shared__ int s[256];
    int t = threadIdx.x;
    int idx = blockIdx.x * 256 + t;
    s[t] = (idx < N_NODES) ? deg[idx] : 0;
    __syncthreads();
#pragma unroll
    for (int off = 128; off > 0; off >>= 1) {
        if (t < off) s[t] += s[t + off];
        __syncthreads();
    }
    if (t == 0) bsum[blockIdx.x] = s[0];
}

// K3b: offs[idx] = (sum of bsum[0..blk)) + exclusive_scan_within_block(deg).
// Block-prefix computed in-kernel from bsum (157 L2-hot loads). invdeg too.
__global__ __launch_bounds__(256) void offs_kernel(const int* __restrict__ deg,
                                                   const int* __restrict__ bsum,
                                                   int* __restrict__ offs,
                                                   float* __restrict__ invdeg) {
    __shared__ int s[256];
    __shared__ int base_s;
    int t = threadIdx.x;

    // block base = sum of bsum[0 .. blockIdx.x)
    int v = (t < blockIdx.x && t < NB) ? bsum[t] : 0;
    s[t] = v;
    __syncthreads();
#pragma unroll
    for (int off = 128; off > 0; off >>= 1) {
        if (t < off) s[t] += s[t + off];
        __syncthreads();
    }
    if (t == 0) base_s = s[0];
    __syncthreads();
    int base = base_s;
    __syncthreads();

    // intra-block exclusive scan of deg
    int idx = blockIdx.x * 256 + t;
    int d = (idx < N_NODES) ? deg[idx] : 0;
    s[t] = d;
    __syncthreads();
#pragma unroll
    for (int off = 1; off < 256; off <<= 1) {
        int u = (t >= off) ? s[t - off] : 0;
        __syncthreads();
        s[t] += u;
        __syncthreads();
    }
    int excl = s[t] - d + base;
    if (idx < N_NODES) {
        offs[idx] = excl;
        invdeg[idx] = (d > 0) ? (1.0f / (float)d) : 0.0f;
        if (idx == N_NODES - 1) offs[N_NODES] = excl + d;   // == N_EDGES
    }
}

// K4: bucket edges by dst: pairs[pos] = (src, bits(ew)) — single 8B store.
__global__ __launch_bounds__(256) void bucket_kernel(const int* __restrict__ src,
                                                     const int* __restrict__ dst,
                                                     const float* __restrict__ ew,
                                                     const int* __restrict__ offs,
                                                     int* __restrict__ cursor,
                                                     int2* __restrict__ pairs) {
    int e = blockIdx.x * 256 + threadIdx.x;
    if (e >= N_EDGES) return;
    int d = dst[e];
    int pos = offs[d] + atomicAdd(&cursor[d], 1);
    pairs[pos] = make_int2(src[e], __float_as_int(ew[e]));
}

// K5: y = x @ W (fp32 vector GEMM; no fp32 MFMA on CDNA4).
// Block = 256 threads computes a 32-row x 128-col tile; W (64KB) + x tile
// (16KB) in LDS. Each thread: 4 rows x 4 cols.
__global__ __launch_bounds__(256) void gemm_xw_kernel(const float* __restrict__ x,
                                                      const float* __restrict__ W,
                                                      float* __restrict__ y) {
    __shared__ float Ws[D * D];             // 64 KB, [k][c] row-major
    __shared__ float xs[GEMM_ROWS * D];     // 16 KB
    const int tid = threadIdx.x;
    const int rowbase = blockIdx.x * GEMM_ROWS;

    float4* Ws4 = reinterpret_cast<float4*>(Ws);
    const float4* W4 = reinterpret_cast<const float4*>(W);
#pragma unroll
    for (int i = 0; i < 16; ++i)                  // 4096 float4 / 256 thr
        Ws4[tid + i * 256] = W4[tid + i * 256];

    float4* xs4 = reinterpret_cast<float4*>(xs);
    const float4* x4 = reinterpret_cast<const float4*>(x) + rowbase * (D / 4);
#pragma unroll
    for (int i = 0; i < GEMM_ROWS * (D / 4) / 256; ++i)   // 1024/256 = 4
        xs4[tid + i * 256] = x4[tid + i * 256];
    __syncthreads();

    const int lane = tid & 31;
    const int rp   = tid >> 5;                    // 0..7 -> rows 4rp..4rp+3
    const float* xr0 = xs + (rp * 4 + 0) * D;
    const float* xr1 = xs + (rp * 4 + 1) * D;
    const float* xr2 = xs + (rp * 4 + 2) * D;
    const float* xr3 = xs + (rp * 4 + 3) * D;

    float4 a0 = {0.f,0.f,0.f,0.f}, a1 = a0, a2 = a0, a3 = a0;
#pragma unroll 4
    for (int k = 0; k < D; ++k) {
        float4 wv = Ws4[k * (D / 4) + lane];      // ds_read_b128
        float x0 = xr0[k], x1 = xr1[k], x2 = xr2[k], x3 = xr3[k];
        a0.x += x0*wv.x; a0.y += x0*wv.y; a0.z += x0*wv.z; a0.w += x0*wv.w;
        a1.x += x1*wv.x; a1.y += x1*wv.y; a1.z += x1*wv.z; a1.w += x1*wv.w;
        a2.x += x2*wv.x; a2.y += x2*wv.y; a2.z += x2*wv.z; a2.w += x2*wv.w;
        a3.x += x3*wv.x; a3.y += x3*wv.y; a3.z += x3*wv.z; a3.w += x3*wv.w;
    }

    float4* y4 = reinterpret_cast<float4*>(y);
    int r0 = rowbase + rp * 4;
    y4[(r0 + 0) * (D / 4) + lane] = a0;
    y4[(r0 + 1) * (D / 4) + lane] = a1;
    y4[(r0 + 2) * (D / 4) + lane] = a2;
    y4[(r0 + 3) * (D / 4) + lane] = a3;
}

// K6: per-node gather-reduce. 32 lanes per node, one float4 per lane.
// Edge pairs loaded lane-parallel in chunks of 32 (8B each), shfl-broadcast.
// out[v][:] = invdeg[v] * sum_e ew_e * y[src_e][:] + b[:]
__global__ __launch_bounds__(256) void gather_kernel(const int* __restrict__ offs,
                                                     const int2* __restrict__ pairs,
                                                     const float* __restrict__ invdeg,
                                                     const float* __restrict__ y,
                                                     const float* __restrict__ b,
                                                     float* __restrict__ out) {
    int gid = blockIdx.x * 256 + threadIdx.x;
    int v    = gid >> 5;
    int part = gid & 31;
    if (v >= N_NODES) return;
    int beg = offs[v];
    int end = offs[v + 1];
    const float4* y4 = reinterpret_cast<const float4*>(y);
    float4 acc = {0.f, 0.f, 0.f, 0.f};
    for (int base = beg; base < end; base += 32) {
        int n = end - base; if (n > 32) n = 32;
        int2 pe = make_int2(0, 0);
        if (part < n) pe = pairs[base + part];
        for (int j = 0; j < n; ++j) {
            int   s = __shfl(pe.x, j, 32);
            float w = __int_as_float(__shfl(pe.y, j, 32));
            float4 t = y4[s * (D / 4) + part];
            acc.x += w * t.x; acc.y += w * t.y; acc.z += w * t.z; acc.w += w * t.w;
        }
    }
    float idv = invdeg[v];
    float4 bv = reinterpret_cast<const float4*>(b)[part];
    acc.x = acc.x * idv + bv.x;
    acc.y = acc.y * idv + bv.y;
    acc.z = acc.z * idv + bv.z;
    acc.w = acc.w * idv + bv.w;
    reinterpret_cast<float4*>(out)[v * (D / 4) + part] = acc;
}

// ---------------------------------------------------------------------------
extern "C" void kernel_launch(void* const* d_in, const int* in_sizes, int n_in,
                              void* d_out, int out_size, void* d_ws, size_t ws_size,
                              hipStream_t stream) {
    const float* x   = (const float*)d_in[0];
    const int*   src = (const int*)d_in[1];
    const int*   dst = (const int*)d_in[2];
    const float* ew  = (const float*)d_in[3];
    const float* W   = (const float*)d_in[4];
    const float* b   = (const float*)d_in[5];
    float* out = (float*)d_out;

    char* ws = (char*)d_ws;
    float* y      = (float*)ws;                       ws += (size_t)N_NODES * D * 4;
    int*   deg    = (int*)ws;                         ws += (size_t)N_NODES * 4;
    int*   cursor = (int*)ws;                         ws += (size_t)N_NODES * 4;
    float* invdeg = (float*)ws;                       ws += (size_t)N_NODES * 4;
    int*   offs   = (int*)ws;                         ws += (size_t)(N_NODES + 16) * 4;
    int*   bsum   = (int*)ws;                         ws += (size_t)((NB + 19) & ~3) * 4;
    int2*  pairs  = (int2*)ws;

    init_kernel<<<(N_NODES + 255) / 256, 256, 0, stream>>>(deg, cursor);
    degree_kernel<<<(N_EDGES + 255) / 256, 256, 0, stream>>>(dst, deg);
    reduce_kernel<<<NB, 256, 0, stream>>>(deg, bsum);
    offs_kernel<<<NB, 256, 0, stream>>>(deg, bsum, offs, invdeg);
    gemm_xw_kernel<<<N_NODES / GEMM_ROWS, 256, 0, stream>>>(x, W, y);
    bucket_kernel<<<(N_EDGES + 255) / 256, 256, 0, stream>>>(src, dst, ew,
                                                             offs, cursor, pairs);
    {
        long long total = (long long)N_NODES * 32;
        gather_kernel<<<(int)((total + 255) / 256), 256, 0, stream>>>(offs, pairs, invdeg, y, b, out);
    }
}